// Round 8
// baseline (306.282 us; speedup 1.0000x reference)
//
#include <hip/hip_runtime.h>
#include <hip/hip_bf16.h>
#include <hip/hip_fp16.h>

// ---------------------------------------------------------------------------
// FakeQuantLinear (Q4_K_M fake-quant + GEMM): out = x @ fq(W)^T + bias
// R14: R13 (best: gemm 126.2us, MfmaUtil 48, conflicts 0) + L2-prewarm of the
//      NEXT K-tile and a counted drain. Mechanism: R6-class loop pays the
//      full memory latency of its own global_load_lds at the vmcnt(0) drain
//      (~500 cyc avg: 37% HBM-miss per FETCH vs requested-volume ratio).
//      Change WHERE latency is paid, not the structure: after the 12 glds of
//      tile k, issue 12 discarded global_load_dword touching tile k+1's lines
//      (prewarm L2 under the compute phase), then s_waitcnt vmcnt(12) (retire
//      exactly the glds; prefetches stay in flight) + raw s_barrier. Next
//      iter's glds hit L2 (~250 cyc drain, m135). Structure, LDS, barrier
//      count, MFMA grouping, 2 blocks/CU: all bit-identical to R13.
//      Barrier #2 stays raw: ds_reads are consumed by MFMAs (compiler lgkm
//      waits) before any wave reaches it. R8 proved this asm-barrier pattern
//      race-free here.
// ---------------------------------------------------------------------------

typedef __attribute__((ext_vector_type(8))) short bf16x8;    // 8 bf16 = 4 VGPRs
typedef __attribute__((ext_vector_type(8))) unsigned short ushort8;
typedef __attribute__((ext_vector_type(4))) float f32x4;     // MFMA acc

__device__ __forceinline__ unsigned short f2bf(float f) {
  unsigned int u = __float_as_uint(f);
  u += 0x7fffu + ((u >> 16) & 1u);
  return (unsigned short)(u >> 16);
}

// ---------------------------------------------------------------------------
// Fused prep kernel (R13: cast 8/thread; quant 8 elems/thread).
// ---------------------------------------------------------------------------
__global__ __launch_bounds__(256) void prep_kernel(
    const float* __restrict__ x, unsigned short* __restrict__ xb,
    const float* __restrict__ w, unsigned short* __restrict__ wq,
    int castBlocks) {
  if ((int)blockIdx.x < castBlocks) {
    const size_t i = ((size_t)blockIdx.x * 256 + threadIdx.x) * 8;
    const float4 a = *(const float4*)(x + i);
    const float4 b = *(const float4*)(x + i + 4);
    ushort8 o = {f2bf(a.x), f2bf(a.y), f2bf(a.z), f2bf(a.w),
                 f2bf(b.x), f2bf(b.y), f2bf(b.z), f2bf(b.w)};
    *(ushort8*)(xb + i) = o;
    return;
  }
  const int qb   = blockIdx.x - castBlocks;
  const int lane = threadIdx.x & 63;
  const int wv   = threadIdx.x >> 6;
  const size_t base = ((size_t)qb * 8 + wv * 2 + (lane >> 5)) * 256 +
                      (size_t)(lane & 31) * 8;
  const float4 v0 = *(const float4*)(w + base);
  const float4 v1 = *(const float4*)(w + base + 4);
  float e[8] = {v0.x, v0.y, v0.z, v0.w, v1.x, v1.y, v1.z, v1.w};

  float mn = e[0], mx = e[0];
#pragma unroll
  for (int k = 1; k < 8; ++k) {
    mn = fminf(mn, e[k]);
    mx = fmaxf(mx, e[k]);
  }
#pragma unroll
  for (int off = 1; off <= 2; off <<= 1) {
    mn = fminf(mn, __shfl_xor(mn, off));
    mx = fmaxf(mx, __shfl_xor(mx, off));
  }
  const float sub_min = fminf(mn, 0.0f);
  const float sub_max = fmaxf(mx, 0.0f);
  const float scale_raw = fmaxf(sub_max - sub_min, 1e-8f) / 15.0f;

  float smn = scale_raw, smx = scale_raw, supermin = sub_min;
#pragma unroll
  for (int off = 4; off <= 16; off <<= 1) {
    smn = fminf(smn, __shfl_xor(smn, off));
    smx = fmaxf(smx, __shfl_xor(smx, off));
    supermin = fminf(supermin, __shfl_xor(supermin, off));
  }
  const float s_range = fmaxf(smx - smn, 1e-8f);
  float s_int = rintf((scale_raw - smn) / s_range * 63.0f);
  s_int = fminf(fmaxf(s_int, 0.0f), 63.0f);
  float scale = s_int / 63.0f * s_range + smn;
  scale = fmaxf(scale, 1e-8f);
  const float inv_scale = 1.0f / scale;

  const float sm  = __half2float(__float2half(supermin));
  const float adj = sub_min - sm;

  ushort8 o;
#pragma unroll
  for (int k = 0; k < 8; ++k) {
    const float t = (e[k] - sm) - adj;
    float qv = rintf(t * inv_scale);
    qv = fminf(fmaxf(qv, 0.0f), 15.0f);
    o[k] = f2bf((qv * scale + adj) + sm);
  }
  *(ushort8*)(wq + base) = o;
}

// ---------------------------------------------------------------------------
// bf16 MFMA GEMM, C[m,n] = sum_k A[m,k]*B[n,k] + bias[n]  (R6/R13 inner loop)
// Block tile 256x128, BK=64, single-buffered; 4 waves (2x2); wave tile
// 128x64 = 8x4 MFMA 16x16x32 per 32-k half. LDS slot-XOR layout (0 conflicts).
// Grid: 1D, XCD-bijective swizzle. NEW: L2 prewarm of tile k+1 + vmcnt(12)
// counted drain (prefetches stay in flight under compute).
// ---------------------------------------------------------------------------
#define BM 256
#define BN 128
#define BK 64

__device__ __forceinline__ void async_cp16(void* lds, const void* g) {
  __builtin_amdgcn_global_load_lds(
      (__attribute__((address_space(1))) void*)(void*)g,
      (__attribute__((address_space(3))) void*)lds, 16, 0, 0);
}

// Discarded 4B load: 64 lanes at 16B stride touch every 128B line of the
// wave's 1024B staging range -> fills L2. Never read; retired by a later
// counted vmcnt boundary. "memory" keeps program order vs the glds builtins
// so vmcnt(12) counts {12 glds oldest, 12 prefetch newest} exactly.
__device__ __forceinline__ void prefetch_l2(const void* g) {
  unsigned int d;
  asm volatile("global_load_dword %0, %1, off" : "=v"(d) : "v"(g) : "memory");
}

__global__ __launch_bounds__(256, 2) void gemm_bt_kernel(
    const unsigned short* __restrict__ A,   // [M][K] bf16 bits
    const unsigned short* __restrict__ B,   // [N][K] bf16 bits (fq weight)
    const float* __restrict__ bias,         // [N]
    float* __restrict__ C,                  // [M][N] f32
    int M, int N, int K) {
  __shared__ unsigned short lds_a[BM * BK];   // 32 KiB
  __shared__ unsigned short lds_b[BN * BK];   // 16 KiB

  const int tid  = threadIdx.x;
  const int lane = tid & 63;
  const int wv   = tid >> 6;
  const int wm   = wv >> 1;          // wave row (128 rows each)
  const int wn   = wv & 1;           // wave col (64 cols each)

  // XCD-bijective swizzle (nwg % 8 == 0 for this shape).
  const int nbx = N / BN;
  const int nwg = (int)gridDim.x;
  const int id  = (int)blockIdx.x;
  int swz = id;
  if ((nwg & 7) == 0) {
    const int cpx = nwg >> 3;
    swz = (id & 7) * cpx + (id >> 3);
  }
  const int bx = swz % nbx;          // N tile (128)
  const int by = swz / nbx;          // M tile (256)

  // staging: issue j covers rows j*32..j*32+31. Thread t -> row j*32+(t>>3),
  // slot t&7. Fetch global chunk (t&7)^((t>>3)&7) so slot s of row r holds
  // s^(r&7) (conflict-free readers).
  const int rloc = tid >> 3;                       // 0..31
  const int csw  = (tid & 7) ^ (rloc & 7);         // swizzled chunk
  const int koff = csw * 8;                        // ushort offset in row

  const unsigned short* gA[8];
  const unsigned short* gB[4];
#pragma unroll
  for (int j = 0; j < 8; ++j)
    gA[j] = A + (size_t)(by * BM + j * 32 + rloc) * K + koff;
#pragma unroll
  for (int j = 0; j < 4; ++j)
    gB[j] = B + (size_t)(bx * BN + j * 32 + rloc) * K + koff;

  f32x4 acc[8][4] = {};

  // fragment addressing: m/n = lane&15; k-chunk q = (lane>>4) + 4*half;
  // stored at slot q^(lane&7).
  const int arow   = wm * 128 + (lane & 15);
  const int brow   = wn * 64 + (lane & 15);
  const int kslot0 = (((lane >> 4) ^ (lane & 7))) * 8;   // half 0
  const int kslot1 = kslot0 ^ 32;                        // half 1 (chunk+4)

  for (int k0 = 0; k0 < K; k0 += BK) {
#pragma unroll
    for (int j = 0; j < 8; ++j)
      async_cp16(lds_a + j * 2048 + tid * 8, gA[j] + k0);
#pragma unroll
    for (int j = 0; j < 4; ++j)
      async_cp16(lds_b + j * 2048 + tid * 8, gB[j] + k0);

    // L2 prewarm of tile k+1 (clamped in-bounds on the last iter).
    const int kp = (k0 + BK < K) ? (k0 + BK) : k0;
#pragma unroll
    for (int j = 0; j < 8; ++j) prefetch_l2(gA[j] + kp);
#pragma unroll
    for (int j = 0; j < 4; ++j) prefetch_l2(gB[j] + kp);

    // Retire exactly the 12 glds (oldest); leave the 12 prefetches in flight
    // to land under the MFMA phase. Then align waves.
    asm volatile("s_waitcnt vmcnt(12)" ::: "memory");
    __builtin_amdgcn_s_barrier();

#pragma unroll
    for (int h = 0; h < 2; ++h) {
      const int ks = h ? kslot1 : kslot0;
      bf16x8 af[8], bfr[4];
#pragma unroll
      for (int i = 0; i < 8; ++i)
        af[i] = *(const bf16x8*)(lds_a + (arow + i * 16) * BK + ks);
#pragma unroll
      for (int j = 0; j < 4; ++j)
        bfr[j] = *(const bf16x8*)(lds_b + (brow + j * 16) * BK + ks);

#pragma unroll
      for (int i = 0; i < 8; ++i)
#pragma unroll
        for (int j = 0; j < 4; ++j)
          acc[i][j] = __builtin_amdgcn_mfma_f32_16x16x32_bf16(af[i], bfr[j],
                                                              acc[i][j], 0, 0, 0);
    }
    // ds_reads are consumed by the MFMAs above (compiler lgkm waits) before
    // any wave reaches this point -> raw barrier suffices to protect LDS.
    __builtin_amdgcn_s_barrier();
  }

  // Epilogue. C/D layout: col = lane&15, row = (lane>>4)*4 + reg
  const int rbase = by * BM + wm * 128 + (lane >> 4) * 4;
  const int cbase = bx * BN + wn * 64 + (lane & 15);
#pragma unroll
  for (int j = 0; j < 4; ++j) {
    const int c = cbase + j * 16;
    const float bv = bias[c];
#pragma unroll
    for (int i = 0; i < 8; ++i) {
#pragma unroll
      for (int r = 0; r < 4; ++r) {
        C[(size_t)(rbase + i * 16 + r) * N + c] = acc[i][j][r] + bv;
      }
    }
  }
}

// ---------------------------------------------------------------------------
extern "C" void kernel_launch(void* const* d_in, const int* in_sizes, int n_in,
                              void* d_out, int out_size, void* d_ws, size_t ws_size,
                              hipStream_t stream) {
  const float* x    = (const float*)d_in[0];
  const float* w    = (const float*)d_in[1];
  const float* bias = (const float*)d_in[2];
  float* out = (float*)d_out;

  const long long xn = in_sizes[0];   // M*K
  const long long wn = in_sizes[1];   // N*K
  const int N = in_sizes[2];
  const int K = (int)(wn / N);
  const int M = (int)(xn / K);

  unsigned short* xb = (unsigned short*)d_ws;
  unsigned short* wb = xb + (size_t)M * K;

  const int castBlocks  = (int)(xn / (256 * 8));    // 8 elems/thread
  const int quantBlocks = (int)(wn / (256 * 8));    // 2048 elems/block
  prep_kernel<<<castBlocks + quantBlocks, 256, 0, stream>>>(x, xb, w, wb,
                                                            castBlocks);
  const int nwg = (N / BN) * (M / BM);
  gemm_bt_kernel<<<nwg, 256, 0, stream>>>(xb, wb, bias, out, M, N, K);
}